// Round 3
// baseline (221.864 us; speedup 1.0000x reference)
//
#include <hip/hip_runtime.h>

// Problem constants
#define BATCH 2
#define TSEQ 2048
#define DIM 1024
#define NH 16
#define HDIM 64
#define MROWS (BATCH * TSEQ)   // 4096

typedef __attribute__((ext_vector_type(4))) float f32x4;
typedef __attribute__((ext_vector_type(8))) short short8;

__device__ __forceinline__ unsigned short f2bf(float f) {
    union { float f; unsigned int u; } x; x.f = f;
    unsigned int r = x.u + 0x7fffu + ((x.u >> 16) & 1u);
    return (unsigned short)(r >> 16);
}

__device__ __forceinline__ float silu_f(float v) {
    return v * __builtin_amdgcn_rcpf(1.f + __expf(-v));
}

__device__ __forceinline__ void gl_lds16(const void* g, void* l) {
    __builtin_amdgcn_global_load_lds(
        (const __attribute__((address_space(1))) void*)g,
        (__attribute__((address_space(3))) void*)l, 16, 0, 0);
}

// swizzled LDS 16B-chunk read: row stride 128B, chunk index XOR (row&7)
__device__ __forceinline__ short8 rd_swz(const unsigned short* base, int row, int chunk) {
    const char* b = (const char*)base;
    return *(const short8*)(b + row * 128 + (((chunk ^ (row & 7)) << 4)));
}

// ---------------- prep: fp32 -> bf16 convert ----------------
__global__ __launch_bounds__(256) void k_convert(const float* __restrict__ in,
                                                 unsigned short* __restrict__ out,
                                                 int n4) {
    int i = blockIdx.x * 256 + threadIdx.x;
    if (i < n4) {
        float4 v = ((const float4*)in)[i];
        union { unsigned short s[4]; uint2 u; } o;
        o.s[0] = f2bf(v.x); o.s[1] = f2bf(v.y); o.s[2] = f2bf(v.z); o.s[3] = f2bf(v.w);
        ((uint2*)out)[i] = o.u;
    }
}

// ---------------- prep: transpose fp32 [R][C] -> bf16 [C][R] ----------------
__global__ __launch_bounds__(256) void k_transpose(const float* __restrict__ in,
                                                   unsigned short* __restrict__ out,
                                                   int R, int C) {
    __shared__ float tile[32][33];
    int tx = threadIdx.x, ty = threadIdx.y; // (32,8)
    int c0 = blockIdx.x * 32, r0 = blockIdx.y * 32;
    #pragma unroll
    for (int i = 0; i < 32; i += 8)
        tile[ty + i][tx] = in[(size_t)(r0 + ty + i) * C + c0 + tx];
    __syncthreads();
    #pragma unroll
    for (int i = 0; i < 32; i += 8)
        out[(size_t)(c0 + ty + i) * R + r0 + tx] = f2bf(tile[tx][ty + i]);
}

// ---------------- prep: transpose bf16 [R][C] -> bf16 [C][R] ----------------
__global__ __launch_bounds__(256) void k_transpose_bf16(const unsigned short* __restrict__ in,
                                                        unsigned short* __restrict__ out,
                                                        int R, int C) {
    __shared__ unsigned short t[64][66];
    int tx = threadIdx.x, ty = threadIdx.y; // (64,4)
    int c0 = blockIdx.x * 64, r0 = blockIdx.y * 64;
    #pragma unroll
    for (int i = 0; i < 64; i += 4)
        t[ty + i][tx] = in[(size_t)(r0 + ty + i) * C + c0 + tx];
    __syncthreads();
    #pragma unroll
    for (int i = 0; i < 64; i += 4)
        out[(size_t)(c0 + ty + i) * R + r0 + tx] = t[tx][ty + i];
}

// ---------------- GEMM: C = A[M,K] @ Bt[N,K]^T, bf16 in, fp32 acc ----------------
// EPI 1: h = silu(acc + bias[n]); split cols into U(f32),V,Q(bf16, *0.125),K(bf16)
// EPI 2: y = acc + bias[n] (fp32 out)
template <int EPI>
__global__ __launch_bounds__(256) void k_gemm(
    const unsigned short* __restrict__ A, const unsigned short* __restrict__ Bt,
    int M, int N, int K, const float* __restrict__ bias,
    float* __restrict__ outU, unsigned short* __restrict__ outV,
    unsigned short* __restrict__ outQ, unsigned short* __restrict__ outK,
    float* __restrict__ outY)
{
    __shared__ __align__(16) unsigned short sA[128 * 32];
    __shared__ __align__(16) unsigned short sB[128 * 32];
    const int tid = threadIdx.x;
    const int bm = blockIdx.x, bn = blockIdx.y;
    const int row0 = bm * 128, col0 = bn * 128;
    const int lane = tid & 63, w = tid >> 6;
    const int wrow = (w >> 1) * 64, wcol = (w & 1) * 64;
    const int lr = lane & 15, lk = lane >> 4;

    f32x4 acc[4][4] = {};

    for (int k0 = 0; k0 < K; k0 += 32) {
        for (int c = tid; c < 512; c += 256) {
            int r = c >> 2, kc = c & 3;
            gl_lds16(A + (size_t)(row0 + r) * K + k0 + kc * 8, sA + c * 8);
            gl_lds16(Bt + (size_t)(col0 + r) * K + k0 + kc * 8, sB + c * 8);
        }
        __syncthreads();
        short8 af[4], bf[4];
        #pragma unroll
        for (int m = 0; m < 4; ++m)
            af[m] = *(const short8*)(sA + (wrow + m * 16 + lr) * 32 + lk * 8);
        #pragma unroll
        for (int n = 0; n < 4; ++n)
            bf[n] = *(const short8*)(sB + (wcol + n * 16 + lr) * 32 + lk * 8);
        #pragma unroll
        for (int m = 0; m < 4; ++m)
            #pragma unroll
            for (int n = 0; n < 4; ++n)
                acc[m][n] = __builtin_amdgcn_mfma_f32_16x16x32_bf16(af[m], bf[n], acc[m][n], 0, 0, 0);
        __syncthreads();
    }

    #pragma unroll
    for (int m = 0; m < 4; ++m) {
        #pragma unroll
        for (int n = 0; n < 4; ++n) {
            int cg = col0 + wcol + n * 16 + lr;
            float bv = bias[cg];
            #pragma unroll
            for (int j = 0; j < 4; ++j) {
                int rg = row0 + wrow + m * 16 + lk * 4 + j;
                float v = acc[m][n][j] + bv;
                if (EPI == 1) {
                    float s = silu_f(v);
                    int sec = cg >> 10, cc = cg & 1023;
                    size_t off = ((size_t)rg << 10) + cc;
                    if (sec == 0) outU[off] = s;
                    else if (sec == 1) outV[off] = f2bf(s);
                    else if (sec == 2) outQ[off] = f2bf(s * 0.125f);  // fold alpha (exact)
                    else outK[off] = f2bf(s);
                } else {
                    outY[(size_t)rg * N + cg] = v;
                }
            }
        }
    }
}

// ---------------- fused pointwise attention ----------------
// grid: 512 blocks x 512 threads. QBLK=128 (8 waves x 16 rows), KVBLK=64.
// bid mapping pairs bb=0/1 of the same (h,qtile) 8 apart -> same XCD, L2 rab reuse.
__global__ __launch_bounds__(512) void k_attn(
    const unsigned short* __restrict__ Qb,
    const unsigned short* __restrict__ Kb,
    const unsigned short* __restrict__ Vt,   // [1024][4096] = V transposed
    const float* __restrict__ rab,
    float* __restrict__ AV)
{
    __shared__ __align__(16) unsigned short sK[2][64 * 64];
    __shared__ __align__(16) unsigned short sVt[2][64 * 64];
    __shared__ __align__(16) unsigned short sP[128 * 64];

    const int tid = threadIdx.x;
    const int lane = tid & 63;
    const int w = tid >> 6;         // 0..7
    const int lr = lane & 15;
    const int lk = lane >> 4;

    const int bid = blockIdx.x;                    // [0,512)
    const int bb = (bid >> 3) & 1;
    const int p = (bid & 7) | ((bid >> 4) << 3);   // [0,256)
    const int h = p & 15;
    const int slot = p >> 4;                       // [0,16)
    const int qt2 = (slot & 1) ? (15 - (slot >> 1)) : (slot >> 1); // balance
    const int q0 = qt2 * 128;
    const int NT = 2 * qt2 + 2;                    // kv tiles for this q-tile

    // Q fragments in registers (wave-private rows)
    const int qra = q0 + w * 16 + lr;
    short8 qreg[2];
    #pragma unroll
    for (int ks = 0; ks < 2; ++ks)
        qreg[ks] = *(const short8*)(Qb + (((size_t)(bb * TSEQ + qra)) << 10)
                                     + h * 64 + ks * 32 + lk * 8);

    int qrow[4]; float invq[4];
    #pragma unroll
    for (int j = 0; j < 4; ++j) {
        qrow[j] = q0 + w * 16 + lk * 4 + j;
        invq[j] = 1.f / (float)(qrow[j] + 1);
    }
    const int wq_lo = q0 + w * 16;       // wave's min q-row
    const int wq_hi = q0 + w * 16 + 15;  // wave's max q-row

    f32x4 acc[4] = {};

    // staging: one 16B chunk per thread per buffer (512 chunks = 64x64 bf16)
    #define STAGE(buf, kt_) do {                                                      \
        int k0s = (kt_) * 64;                                                         \
        int rr = tid >> 3, kc = tid & 7, kcs = kc ^ (rr & 7);                         \
        gl_lds16(Kb + (((size_t)(bb * TSEQ + k0s + rr)) << 10) + h * 64 + kcs * 8,    \
                 sK[buf] + tid * 8);                                                  \
        gl_lds16(Vt + (((size_t)(h * 64 + rr)) << 12) + bb * TSEQ + k0s + kcs * 8,    \
                 sVt[buf] + tid * 8);                                                 \
    } while (0)

    const float* rabh = rab + (size_t)h * TSEQ * TSEQ;

    STAGE(0, 0);
    // rab for kt=0 into registers
    float rvc[4][4];
    #pragma unroll
    for (int nt = 0; nt < 4; ++nt)
        #pragma unroll
        for (int j = 0; j < 4; ++j)
            rvc[nt][j] = rabh[(size_t)qrow[j] * TSEQ + nt * 16 + lr];
    __syncthreads();

    int cur = 0;
    for (int kt = 0; kt < NT; ++kt) {
        const int k0 = kt * 64;
        const bool have_next = (kt + 1 < NT);
        if (have_next) STAGE(cur ^ 1, kt + 1);

        // prefetch next iter's rab into regs (issued a full iteration early)
        float rvn[4][4];
        const bool next_active = have_next && (k0 + 64 <= wq_hi);
        if (next_active) {
            #pragma unroll
            for (int nt = 0; nt < 4; ++nt)
                #pragma unroll
                for (int j = 0; j < 4; ++j)
                    rvn[nt][j] = rabh[(size_t)qrow[j] * TSEQ + k0 + 64 + nt * 16 + lr];
        }

        const bool active = (k0 <= wq_hi);
        if (active) {
            // S = Q K^T
            f32x4 s[4] = {};
            #pragma unroll
            for (int ks = 0; ks < 2; ++ks) {
                #pragma unroll
                for (int nt = 0; nt < 4; ++nt)
                    s[nt] = __builtin_amdgcn_mfma_f32_16x16x32_bf16(
                        qreg[ks], rd_swz(sK[cur], nt * 16 + lr, ks * 4 + lk), s[nt], 0, 0, 0);
            }

            // P = silu(s + rab) / (q+1), causal; store to wave-private sP strip
            const bool full = (k0 + 63 <= wq_lo);
            char* pb = (char*)sP;
            #pragma unroll
            for (int nt = 0; nt < 4; ++nt) {
                int k = k0 + nt * 16 + lr;
                #pragma unroll
                for (int j = 0; j < 4; ++j) {
                    int prow = w * 16 + lk * 4 + j;
                    float v = s[nt][j] + rvc[nt][j];
                    float pv = (full || k <= qrow[j]) ? silu_f(v) * invq[j] : 0.f;
                    *(unsigned short*)(pb + prow * 128 + (((nt * 16 + lr) * 2) ^ ((prow & 7) << 4)))
                        = f2bf(pv);
                }
            }

            // AV += P @ V
            #pragma unroll
            for (int ks = 0; ks < 2; ++ks) {
                short8 ap = rd_swz(sP, w * 16 + lr, ks * 4 + lk);
                #pragma unroll
                for (int dt = 0; dt < 4; ++dt)
                    acc[dt] = __builtin_amdgcn_mfma_f32_16x16x32_bf16(
                        ap, rd_swz(sVt[cur], dt * 16 + lr, ks * 4 + lk), acc[dt], 0, 0, 0);
            }
        }

        if (next_active) {
            #pragma unroll
            for (int nt = 0; nt < 4; ++nt)
                #pragma unroll
                for (int j = 0; j < 4; ++j)
                    rvc[nt][j] = rvn[nt][j];
        }

        __syncthreads();
        cur ^= 1;
    }
    #undef STAGE

    #pragma unroll
    for (int dt = 0; dt < 4; ++dt)
        #pragma unroll
        for (int j = 0; j < 4; ++j)
            AV[(((size_t)(bb * TSEQ + qrow[j])) << 10) + h * 64 + dt * 16 + lr] = acc[dt][j];
}

// ---------------- LayerNorm(AV) * U -> z (bf16) ----------------
__global__ __launch_bounds__(256) void k_ln(const float* __restrict__ AV,
                                            const float* __restrict__ U,
                                            const float* __restrict__ lnw,
                                            const float* __restrict__ lnb,
                                            unsigned short* __restrict__ z) {
    __shared__ float red[8];
    const int row = blockIdx.x, tid = threadIdx.x;
    float4 v = ((const float4*)(AV + ((size_t)row << 10)))[tid];
    float s = v.x + v.y + v.z + v.w;
    float s2 = v.x * v.x + v.y * v.y + v.z * v.z + v.w * v.w;
    #pragma unroll
    for (int o = 32; o > 0; o >>= 1) { s += __shfl_xor(s, o); s2 += __shfl_xor(s2, o); }
    const int w = tid >> 6;
    if ((tid & 63) == 0) { red[w] = s; red[4 + w] = s2; }
    __syncthreads();
    s = red[0] + red[1] + red[2] + red[3];
    s2 = red[4] + red[5] + red[6] + red[7];
    const float mu = s * (1.f / 1024.f);
    const float var = s2 * (1.f / 1024.f) - mu * mu;
    const float rstd = rsqrtf(var + 1e-5f);
    float4 uw = ((const float4*)(U + ((size_t)row << 10)))[tid];
    float4 lw = ((const float4*)lnw)[tid];
    float4 lb = ((const float4*)lnb)[tid];
    union { unsigned short o[4]; uint2 u; } ov;
    ov.o[0] = f2bf(((v.x - mu) * rstd * lw.x + lb.x) * uw.x);
    ov.o[1] = f2bf(((v.y - mu) * rstd * lw.y + lb.y) * uw.y);
    ov.o[2] = f2bf(((v.z - mu) * rstd * lw.z + lb.z) * uw.z);
    ov.o[3] = f2bf(((v.w - mu) * rstd * lw.w + lb.w) * uw.w);
    ((uint2*)z)[((size_t)row << 8) + tid] = ov.u;
}

extern "C" void kernel_launch(void* const* d_in, const int* in_sizes, int n_in,
                              void* d_out, int out_size, void* d_ws, size_t ws_size,
                              hipStream_t stream) {
    const float* x     = (const float*)d_in[0];
    const float* rab   = (const float*)d_in[2];
    const float* W_in  = (const float*)d_in[3];
    const float* b_in  = (const float*)d_in[4];
    const float* W_out = (const float*)d_in[5];
    const float* b_out = (const float*)d_in[6];
    const float* ln_w  = (const float*)d_in[7];
    const float* ln_b  = (const float*)d_in[8];
    float* y = (float*)d_out;

    char* ws = (char*)d_ws;
    size_t off = 0;
    auto alloc = [&](size_t bytes) -> void* {
        void* p = ws + off;
        off += (bytes + 255) & ~(size_t)255;
        return p;
    };
    unsigned short* WinT  = (unsigned short*)alloc((size_t)4096 * 1024 * 2);
    unsigned short* WoutT = (unsigned short*)alloc((size_t)1024 * 1024 * 2);
    unsigned short* xb    = (unsigned short*)alloc((size_t)MROWS * DIM * 2);
    float*          Ubuf  = (float*)alloc((size_t)MROWS * DIM * 4);
    unsigned short* Vb    = (unsigned short*)alloc((size_t)MROWS * DIM * 2);
    unsigned short* Qb    = (unsigned short*)alloc((size_t)MROWS * DIM * 2);
    unsigned short* Kb    = (unsigned short*)alloc((size_t)MROWS * DIM * 2);
    unsigned short* Vtb   = (unsigned short*)alloc((size_t)DIM * MROWS * 2);
    float*          AV    = (float*)alloc((size_t)MROWS * DIM * 4);
    unsigned short* z     = (unsigned short*)alloc((size_t)MROWS * DIM * 2);

    // prep
    k_convert<<<dim3(4096), dim3(256), 0, stream>>>(x, xb, MROWS * DIM / 4);
    k_transpose<<<dim3(128, 32), dim3(32, 8), 0, stream>>>(W_in, WinT, 1024, 4096);
    k_transpose<<<dim3(32, 32), dim3(32, 8), 0, stream>>>(W_out, WoutT, 1024, 1024);
    // GEMM1: h = silu(x @ W_in + b_in) -> U,V,Q(*alpha),K
    k_gemm<1><<<dim3(32, 32), dim3(256), 0, stream>>>(xb, WinT, MROWS, 4096, 1024,
                                                      b_in, Ubuf, Vb, Qb, Kb, nullptr);
    // V -> V^T (global), so attention can stage both K and V^T via global_load_lds
    k_transpose_bf16<<<dim3(16, 64), dim3(64, 4), 0, stream>>>(Vb, Vtb, MROWS, DIM);
    // attention
    k_attn<<<dim3(512), dim3(512), 0, stream>>>(Qb, Kb, Vtb, rab, AV);
    // LN * U
    k_ln<<<dim3(MROWS), dim3(256), 0, stream>>>(AV, Ubuf, ln_w, ln_b, z);
    // GEMM2: y = z @ W_out + b_out
    k_gemm<2><<<dim3(32, 8), dim3(256), 0, stream>>>(z, WoutT, MROWS, 1024, 1024,
                                                     b_out, nullptr, nullptr, nullptr, nullptr, y);
}

// Round 4
// 195.250 us; speedup vs baseline: 1.1363x; 1.1363x over previous
//
#include <hip/hip_runtime.h>

// Problem constants
#define BATCH 2
#define TSEQ 2048
#define DIM 1024
#define NH 16
#define HDIM 64
#define MROWS (BATCH * TSEQ)   // 4096

typedef __attribute__((ext_vector_type(4))) float f32x4;
typedef __attribute__((ext_vector_type(8))) short short8;

__device__ __forceinline__ unsigned short f2bf(float f) {
    union { float f; unsigned int u; } x; x.f = f;
    unsigned int r = x.u + 0x7fffu + ((x.u >> 16) & 1u);
    return (unsigned short)(r >> 16);
}

__device__ __forceinline__ float silu_f(float v) {
    return v * __builtin_amdgcn_rcpf(1.f + __expf(-v));
}

__device__ __forceinline__ void gl_lds16(const void* g, void* l) {
    __builtin_amdgcn_global_load_lds(
        (const __attribute__((address_space(1))) void*)g,
        (__attribute__((address_space(3))) void*)l, 16, 0, 0);
}

// swizzled LDS 16B-chunk read: row stride 128B, chunk index XOR (row&7)
__device__ __forceinline__ short8 rd_swz(const unsigned short* base, int row, int chunk) {
    const char* b = (const char*)base;
    return *(const short8*)(b + row * 128 + (((chunk ^ (row & 7)) << 4)));
}

// ---------------- prep: fp32 -> bf16 convert ----------------
__global__ __launch_bounds__(256) void k_convert(const float* __restrict__ in,
                                                 unsigned short* __restrict__ out,
                                                 int n4) {
    int i = blockIdx.x * 256 + threadIdx.x;
    if (i < n4) {
        float4 v = ((const float4*)in)[i];
        union { unsigned short s[4]; uint2 u; } o;
        o.s[0] = f2bf(v.x); o.s[1] = f2bf(v.y); o.s[2] = f2bf(v.z); o.s[3] = f2bf(v.w);
        ((uint2*)out)[i] = o.u;
    }
}

// ---------------- prep: transpose fp32 [R][C] -> bf16 [C][R] ----------------
__global__ __launch_bounds__(256) void k_transpose(const float* __restrict__ in,
                                                   unsigned short* __restrict__ out,
                                                   int R, int C) {
    __shared__ float tile[32][33];
    int tx = threadIdx.x, ty = threadIdx.y; // (32,8)
    int c0 = blockIdx.x * 32, r0 = blockIdx.y * 32;
    #pragma unroll
    for (int i = 0; i < 32; i += 8)
        tile[ty + i][tx] = in[(size_t)(r0 + ty + i) * C + c0 + tx];
    __syncthreads();
    #pragma unroll
    for (int i = 0; i < 32; i += 8)
        out[(size_t)(c0 + ty + i) * R + r0 + tx] = f2bf(tile[tx][ty + i]);
}

// ---------------- prep: transpose bf16 [R][C] -> bf16 [C][R] ----------------
__global__ __launch_bounds__(256) void k_transpose_bf16(const unsigned short* __restrict__ in,
                                                        unsigned short* __restrict__ out,
                                                        int R, int C) {
    __shared__ unsigned short t[64][66];
    int tx = threadIdx.x, ty = threadIdx.y; // (64,4)
    int c0 = blockIdx.x * 64, r0 = blockIdx.y * 64;
    #pragma unroll
    for (int i = 0; i < 64; i += 4)
        t[ty + i][tx] = in[(size_t)(r0 + ty + i) * C + c0 + tx];
    __syncthreads();
    #pragma unroll
    for (int i = 0; i < 64; i += 4)
        out[(size_t)(c0 + ty + i) * R + r0 + tx] = t[tx][ty + i];
}

// ---------------- GEMM: C = A[M,K] @ Bt[N,K]^T, bf16 in, fp32 acc ----------------
// EPI 1: h = silu(acc + bias[n]); split cols into U(f32),V,Q(bf16, *0.125),K(bf16)
// EPI 2: y = acc + bias[n] (fp32 out)
template <int EPI>
__global__ __launch_bounds__(256) void k_gemm(
    const unsigned short* __restrict__ A, const unsigned short* __restrict__ Bt,
    int M, int N, int K, const float* __restrict__ bias,
    float* __restrict__ outU, unsigned short* __restrict__ outV,
    unsigned short* __restrict__ outQ, unsigned short* __restrict__ outK,
    float* __restrict__ outY)
{
    __shared__ __align__(16) unsigned short sA[128 * 32];
    __shared__ __align__(16) unsigned short sB[128 * 32];
    const int tid = threadIdx.x;
    const int bm = blockIdx.x, bn = blockIdx.y;
    const int row0 = bm * 128, col0 = bn * 128;
    const int lane = tid & 63, w = tid >> 6;
    const int wrow = (w >> 1) * 64, wcol = (w & 1) * 64;
    const int lr = lane & 15, lk = lane >> 4;

    f32x4 acc[4][4] = {};

    for (int k0 = 0; k0 < K; k0 += 32) {
        for (int c = tid; c < 512; c += 256) {
            int r = c >> 2, kc = c & 3;
            gl_lds16(A + (size_t)(row0 + r) * K + k0 + kc * 8, sA + c * 8);
            gl_lds16(Bt + (size_t)(col0 + r) * K + k0 + kc * 8, sB + c * 8);
        }
        __syncthreads();
        short8 af[4], bf[4];
        #pragma unroll
        for (int m = 0; m < 4; ++m)
            af[m] = *(const short8*)(sA + (wrow + m * 16 + lr) * 32 + lk * 8);
        #pragma unroll
        for (int n = 0; n < 4; ++n)
            bf[n] = *(const short8*)(sB + (wcol + n * 16 + lr) * 32 + lk * 8);
        #pragma unroll
        for (int m = 0; m < 4; ++m)
            #pragma unroll
            for (int n = 0; n < 4; ++n)
                acc[m][n] = __builtin_amdgcn_mfma_f32_16x16x32_bf16(af[m], bf[n], acc[m][n], 0, 0, 0);
        __syncthreads();
    }

    #pragma unroll
    for (int m = 0; m < 4; ++m) {
        #pragma unroll
        for (int n = 0; n < 4; ++n) {
            int cg = col0 + wcol + n * 16 + lr;
            float bv = bias[cg];
            #pragma unroll
            for (int j = 0; j < 4; ++j) {
                int rg = row0 + wrow + m * 16 + lk * 4 + j;
                float v = acc[m][n][j] + bv;
                if (EPI == 1) {
                    float s = silu_f(v);
                    int sec = cg >> 10, cc = cg & 1023;
                    size_t off = ((size_t)rg << 10) + cc;
                    if (sec == 0) outU[off] = s;
                    else if (sec == 1) outV[off] = f2bf(s);
                    else if (sec == 2) outQ[off] = f2bf(s * 0.125f);  // fold alpha (exact)
                    else outK[off] = f2bf(s);
                } else {
                    outY[(size_t)rg * N + cg] = v;
                }
            }
        }
    }
}

// ---------------- fused pointwise attention ----------------
// grid: 1024 blocks x 256 threads; QBLK=64 (4 waves x 16 rows), KVBLK=64.
// Mapping: bids c, c+256, c+512, c+768 land on one CU under round-robin:
// (bb0,qt=r), (bb0,31-r), (bb1,r), (bb1,31-r) -> per-CU iter sum == 66 (balanced)
// and bb0/bb1 twins of the same (h,qt) are co-resident -> rab L1/L2 reuse.
__global__ __launch_bounds__(256, 4) void k_attn(
    const unsigned short* __restrict__ Qb,
    const unsigned short* __restrict__ Kb,
    const unsigned short* __restrict__ Vt,   // [1024][4096] = V transposed
    const float* __restrict__ rab,
    float* __restrict__ AV)
{
    __shared__ __align__(16) unsigned short sK[2][64 * 64];
    __shared__ __align__(16) unsigned short sVt[2][64 * 64];
    __shared__ __align__(16) unsigned short sP[64 * 64];   // 40 KB total

    const int tid = threadIdx.x;
    const int lane = tid & 63;
    const int w = tid >> 6;        // 0..3
    const int lr = lane & 15;
    const int lk = lane >> 4;

    const int bid = blockIdx.x;
    const int idx = bid & 255;
    const int g = bid >> 8;
    const int h = idx & 15;
    const int r_ = idx >> 4;
    const int bb = g >> 1;
    const int qt = (g & 1) ? (31 - r_) : r_;
    const int q0 = qt * 64;

    // Q fragments in registers (wave-private rows q0 + w*16 + lr)
    short8 qreg[2];
    #pragma unroll
    for (int ks = 0; ks < 2; ++ks)
        qreg[ks] = *(const short8*)(Qb + (((size_t)(bb * TSEQ + q0 + w * 16 + lr)) << 10)
                                     + h * 64 + ks * 32 + lk * 8);

    int qrow[4]; float invq[4];
    #pragma unroll
    for (int j = 0; j < 4; ++j) {
        qrow[j] = q0 + w * 16 + lk * 4 + j;
        invq[j] = 1.f / (float)(qrow[j] + 1);
    }

    f32x4 acc[4] = {};

    // staging: 2 chunks/thread for each of K and Vt (64x64 bf16 tiles)
    #define STAGE(buf, kt_) do {                                                      \
        int k0s = (kt_) * 64;                                                         \
        for (int c = tid; c < 512; c += 256) {                                        \
            int rr = c >> 3, kc = c & 7;                                              \
            int kcs = kc ^ (rr & 7);                                                  \
            gl_lds16(Kb + (((size_t)(bb * TSEQ + k0s + rr)) << 10) + h * 64 + kcs * 8,\
                     sK[buf] + c * 8);                                                \
            gl_lds16(Vt + (((size_t)(h * 64 + rr)) << 12) + bb * TSEQ + k0s + kcs * 8,\
                     sVt[buf] + c * 8);                                               \
        }                                                                             \
    } while (0)

    const float* rabh = rab + (size_t)h * TSEQ * TSEQ;

    STAGE(0, 0);
    // rab for kt=0 into registers
    float rvc[4][4];
    #pragma unroll
    for (int nt = 0; nt < 4; ++nt)
        #pragma unroll
        for (int j = 0; j < 4; ++j)
            rvc[nt][j] = rabh[(size_t)qrow[j] * TSEQ + nt * 16 + lr];
    __syncthreads();

    int cur = 0;
    for (int kt = 0; kt <= qt; ++kt) {
        const int k0 = kt * 64;
        const bool have_next = (kt < qt);
        if (have_next) STAGE(cur ^ 1, kt + 1);

        // prefetch next iteration's rab into regs (full iteration of cover)
        float rvn[4][4];
        if (have_next) {
            #pragma unroll
            for (int nt = 0; nt < 4; ++nt)
                #pragma unroll
                for (int j = 0; j < 4; ++j)
                    rvn[nt][j] = rabh[(size_t)qrow[j] * TSEQ + k0 + 64 + nt * 16 + lr];
        }

        // S = Q K^T  (alpha pre-folded into Q)
        f32x4 s[4] = {};
        #pragma unroll
        for (int ks = 0; ks < 2; ++ks) {
            #pragma unroll
            for (int nt = 0; nt < 4; ++nt)
                s[nt] = __builtin_amdgcn_mfma_f32_16x16x32_bf16(
                    qreg[ks], rd_swz(sK[cur], nt * 16 + lr, ks * 4 + lk), s[nt], 0, 0, 0);
        }

        // P = silu(s + rab) / (q+1), causal; store to wave-private sP strip
        const bool full = (kt < qt);
        char* pb = (char*)sP;
        #pragma unroll
        for (int nt = 0; nt < 4; ++nt) {
            int k = k0 + nt * 16 + lr;
            #pragma unroll
            for (int j = 0; j < 4; ++j) {
                int prow = w * 16 + lk * 4 + j;
                float v = s[nt][j] + rvc[nt][j];
                float pv = (full || k <= qrow[j]) ? silu_f(v) * invq[j] : 0.f;
                *(unsigned short*)(pb + prow * 128 + (((nt * 16 + lr) * 2) ^ ((prow & 7) << 4)))
                    = f2bf(pv);
            }
        }

        // AV += P @ V
        #pragma unroll
        for (int ks = 0; ks < 2; ++ks) {
            short8 ap = rd_swz(sP, w * 16 + lr, ks * 4 + lk);
            #pragma unroll
            for (int dt = 0; dt < 4; ++dt)
                acc[dt] = __builtin_amdgcn_mfma_f32_16x16x32_bf16(
                    ap, rd_swz(sVt[cur], dt * 16 + lr, ks * 4 + lk), acc[dt], 0, 0, 0);
        }

        if (have_next) {
            #pragma unroll
            for (int nt = 0; nt < 4; ++nt)
                #pragma unroll
                for (int j = 0; j < 4; ++j)
                    rvc[nt][j] = rvn[nt][j];
        }

        __syncthreads();
        cur ^= 1;
    }
    #undef STAGE

    #pragma unroll
    for (int dt = 0; dt < 4; ++dt)
        #pragma unroll
        for (int j = 0; j < 4; ++j)
            AV[(((size_t)(bb * TSEQ + qrow[j])) << 10) + h * 64 + dt * 16 + lr] = acc[dt][j];
}

// ---------------- LayerNorm(AV) * U -> z (bf16) ----------------
__global__ __launch_bounds__(256) void k_ln(const float* __restrict__ AV,
                                            const float* __restrict__ U,
                                            const float* __restrict__ lnw,
                                            const float* __restrict__ lnb,
                                            unsigned short* __restrict__ z) {
    __shared__ float red[8];
    const int row = blockIdx.x, tid = threadIdx.x;
    float4 v = ((const float4*)(AV + ((size_t)row << 10)))[tid];
    float s = v.x + v.y + v.z + v.w;
    float s2 = v.x * v.x + v.y * v.y + v.z * v.z + v.w * v.w;
    #pragma unroll
    for (int o = 32; o > 0; o >>= 1) { s += __shfl_xor(s, o); s2 += __shfl_xor(s2, o); }
    const int w = tid >> 6;
    if ((tid & 63) == 0) { red[w] = s; red[4 + w] = s2; }
    __syncthreads();
    s = red[0] + red[1] + red[2] + red[3];
    s2 = red[4] + red[5] + red[6] + red[7];
    const float mu = s * (1.f / 1024.f);
    const float var = s2 * (1.f / 1024.f) - mu * mu;
    const float rstd = rsqrtf(var + 1e-5f);
    float4 uw = ((const float4*)(U + ((size_t)row << 10)))[tid];
    float4 lw = ((const float4*)lnw)[tid];
    float4 lb = ((const float4*)lnb)[tid];
    union { unsigned short o[4]; uint2 u; } ov;
    ov.o[0] = f2bf(((v.x - mu) * rstd * lw.x + lb.x) * uw.x);
    ov.o[1] = f2bf(((v.y - mu) * rstd * lw.y + lb.y) * uw.y);
    ov.o[2] = f2bf(((v.z - mu) * rstd * lw.z + lb.z) * uw.z);
    ov.o[3] = f2bf(((v.w - mu) * rstd * lw.w + lb.w) * uw.w);
    ((uint2*)z)[((size_t)row << 8) + tid] = ov.u;
}

extern "C" void kernel_launch(void* const* d_in, const int* in_sizes, int n_in,
                              void* d_out, int out_size, void* d_ws, size_t ws_size,
                              hipStream_t stream) {
    const float* x     = (const float*)d_in[0];
    const float* rab   = (const float*)d_in[2];
    const float* W_in  = (const float*)d_in[3];
    const float* b_in  = (const float*)d_in[4];
    const float* W_out = (const float*)d_in[5];
    const float* b_out = (const float*)d_in[6];
    const float* ln_w  = (const float*)d_in[7];
    const float* ln_b  = (const float*)d_in[8];
    float* y = (float*)d_out;

    char* ws = (char*)d_ws;
    size_t off = 0;
    auto alloc = [&](size_t bytes) -> void* {
        void* p = ws + off;
        off += (bytes + 255) & ~(size_t)255;
        return p;
    };
    unsigned short* WinT  = (unsigned short*)alloc((size_t)4096 * 1024 * 2);
    unsigned short* WoutT = (unsigned short*)alloc((size_t)1024 * 1024 * 2);
    unsigned short* xb    = (unsigned short*)alloc((size_t)MROWS * DIM * 2);
    float*          Ubuf  = (float*)alloc((size_t)MROWS * DIM * 4);
    unsigned short* Vb    = (unsigned short*)alloc((size_t)MROWS * DIM * 2);
    unsigned short* Qb    = (unsigned short*)alloc((size_t)MROWS * DIM * 2);
    unsigned short* Kb    = (unsigned short*)alloc((size_t)MROWS * DIM * 2);
    unsigned short* Vtb   = (unsigned short*)alloc((size_t)DIM * MROWS * 2);
    float*          AV    = (float*)alloc((size_t)MROWS * DIM * 4);
    unsigned short* z     = (unsigned short*)alloc((size_t)MROWS * DIM * 2);

    // prep
    k_convert<<<dim3(4096), dim3(256), 0, stream>>>(x, xb, MROWS * DIM / 4);
    k_transpose<<<dim3(128, 32), dim3(32, 8), 0, stream>>>(W_in, WinT, 1024, 4096);
    k_transpose<<<dim3(32, 32), dim3(32, 8), 0, stream>>>(W_out, WoutT, 1024, 1024);
    // GEMM1: h = silu(x @ W_in + b_in) -> U,V,Q(*alpha),K
    k_gemm<1><<<dim3(32, 32), dim3(256), 0, stream>>>(xb, WinT, MROWS, 4096, 1024,
                                                      b_in, Ubuf, Vb, Qb, Kb, nullptr);
    // V -> V^T (global), so attention can stage both K and V^T via global_load_lds
    k_transpose_bf16<<<dim3(16, 64), dim3(64, 4), 0, stream>>>(Vb, Vtb, MROWS, DIM);
    // attention
    k_attn<<<dim3(1024), dim3(256), 0, stream>>>(Qb, Kb, Vtb, rab, AV);
    // LN * U
    k_ln<<<dim3(MROWS), dim3(256), 0, stream>>>(AV, Ubuf, ln_w, ln_b, z);
    // GEMM2: y = z @ W_out + b_out
    k_gemm<2><<<dim3(32, 8), dim3(256), 0, stream>>>(z, WoutT, MROWS, 1024, 1024,
                                                     b_out, nullptr, nullptr, nullptr, nullptr, y);
}

// Round 6
// 186.359 us; speedup vs baseline: 1.1905x; 1.0477x over previous
//
#include <hip/hip_runtime.h>

// Problem constants
#define BATCH 2
#define TSEQ 2048
#define DIM 1024
#define NH 16
#define HDIM 64
#define MROWS (BATCH * TSEQ)   // 4096

typedef __attribute__((ext_vector_type(4))) float f32x4;
typedef __attribute__((ext_vector_type(8))) short short8;

__device__ __forceinline__ unsigned short f2bf(float f) {
    union { float f; unsigned int u; } x; x.f = f;
    unsigned int r = x.u + 0x7fffu + ((x.u >> 16) & 1u);
    return (unsigned short)(r >> 16);
}

__device__ __forceinline__ float silu_f(float v) {
    return v * __builtin_amdgcn_rcpf(1.f + __expf(-v));
}

__device__ __forceinline__ void gl_lds16(const void* g, void* l) {
    __builtin_amdgcn_global_load_lds(
        (const __attribute__((address_space(1))) void*)g,
        (__attribute__((address_space(3))) void*)l, 16, 0, 0);
}

// swizzled LDS 16B-chunk read: row stride 128B, chunk index XOR (row&7)
__device__ __forceinline__ short8 rd_swz(const unsigned short* base, int row, int chunk) {
    const char* b = (const char*)base;
    return *(const short8*)(b + row * 128 + (((chunk ^ (row & 7)) << 4)));
}

// ---------------- prep: fp32 -> bf16 convert ----------------
__global__ __launch_bounds__(256) void k_convert(const float* __restrict__ in,
                                                 unsigned short* __restrict__ out,
                                                 int n4) {
    int i = blockIdx.x * 256 + threadIdx.x;
    if (i < n4) {
        float4 v = ((const float4*)in)[i];
        union { unsigned short s[4]; uint2 u; } o;
        o.s[0] = f2bf(v.x); o.s[1] = f2bf(v.y); o.s[2] = f2bf(v.z); o.s[3] = f2bf(v.w);
        ((uint2*)out)[i] = o.u;
    }
}

// ---------------- prep: transpose fp32 [R][C] -> bf16 [C][R] ----------------
__global__ __launch_bounds__(256) void k_transpose(const float* __restrict__ in,
                                                   unsigned short* __restrict__ out,
                                                   int R, int C) {
    __shared__ float tile[32][33];
    int tx = threadIdx.x, ty = threadIdx.y; // (32,8)
    int c0 = blockIdx.x * 32, r0 = blockIdx.y * 32;
    #pragma unroll
    for (int i = 0; i < 32; i += 8)
        tile[ty + i][tx] = in[(size_t)(r0 + ty + i) * C + c0 + tx];
    __syncthreads();
    #pragma unroll
    for (int i = 0; i < 32; i += 8)
        out[(size_t)(c0 + ty + i) * R + r0 + tx] = f2bf(tile[tx][ty + i]);
}

// ---------------- GEMM: C = A[M,K] @ Bt[N,K]^T, bf16 in, fp32 acc ----------------
// EPI 1: h = silu(acc + bias[n]); cols -> U(f32), V^T(bf16, transposed store),
//        Q(bf16, *0.125), K(bf16)
// EPI 2: y = acc + bias[n] (fp32 out)
template <int EPI>
__global__ __launch_bounds__(256) void k_gemm(
    const unsigned short* __restrict__ A, const unsigned short* __restrict__ Bt,
    int M, int N, int K, const float* __restrict__ bias,
    float* __restrict__ outU, unsigned short* __restrict__ outVt,
    unsigned short* __restrict__ outQ, unsigned short* __restrict__ outK,
    float* __restrict__ outY)
{
    __shared__ __align__(16) unsigned short sA[128 * 32];
    __shared__ __align__(16) unsigned short sB[128 * 32];
    const int tid = threadIdx.x;
    const int bm = blockIdx.x, bn = blockIdx.y;
    const int row0 = bm * 128, col0 = bn * 128;
    const int lane = tid & 63, w = tid >> 6;
    const int wrow = (w >> 1) * 64, wcol = (w & 1) * 64;
    const int lr = lane & 15, lk = lane >> 4;

    f32x4 acc[4][4] = {};

    for (int k0 = 0; k0 < K; k0 += 32) {
        for (int c = tid; c < 512; c += 256) {
            int r = c >> 2, kc = c & 3;
            gl_lds16(A + (size_t)(row0 + r) * K + k0 + kc * 8, sA + c * 8);
            gl_lds16(Bt + (size_t)(col0 + r) * K + k0 + kc * 8, sB + c * 8);
        }
        __syncthreads();
        short8 af[4], bf[4];
        #pragma unroll
        for (int m = 0; m < 4; ++m)
            af[m] = *(const short8*)(sA + (wrow + m * 16 + lr) * 32 + lk * 8);
        #pragma unroll
        for (int n = 0; n < 4; ++n)
            bf[n] = *(const short8*)(sB + (wcol + n * 16 + lr) * 32 + lk * 8);
        #pragma unroll
        for (int m = 0; m < 4; ++m)
            #pragma unroll
            for (int n = 0; n < 4; ++n)
                acc[m][n] = __builtin_amdgcn_mfma_f32_16x16x32_bf16(af[m], bf[n], acc[m][n], 0, 0, 0);
        __syncthreads();
    }

    #pragma unroll
    for (int m = 0; m < 4; ++m) {
        #pragma unroll
        for (int n = 0; n < 4; ++n) {
            int cg = col0 + wcol + n * 16 + lr;
            float bv = bias[cg];
            int rg0 = row0 + wrow + m * 16 + lk * 4;
            if (EPI == 1) {
                float sv[4];
                #pragma unroll
                for (int j = 0; j < 4; ++j)
                    sv[j] = silu_f(acc[m][n][j] + bv);
                int sec = cg >> 10, cc = cg & 1023;
                if (sec == 0) {
                    #pragma unroll
                    for (int j = 0; j < 4; ++j)
                        outU[((size_t)(rg0 + j) << 10) + cc] = sv[j];
                } else if (sec == 1) {
                    // transposed store: Vt[cc][rg0..rg0+3] packed 8B
                    union { unsigned short s[4]; uint2 u; } pk;
                    #pragma unroll
                    for (int j = 0; j < 4; ++j) pk.s[j] = f2bf(sv[j]);
                    *(uint2*)(outVt + ((size_t)cc << 12) + rg0) = pk.u;
                } else if (sec == 2) {
                    #pragma unroll
                    for (int j = 0; j < 4; ++j)
                        outQ[((size_t)(rg0 + j) << 10) + cc] = f2bf(sv[j] * 0.125f);
                } else {
                    #pragma unroll
                    for (int j = 0; j < 4; ++j)
                        outK[((size_t)(rg0 + j) << 10) + cc] = f2bf(sv[j]);
                }
            } else {
                #pragma unroll
                for (int j = 0; j < 4; ++j)
                    outY[(size_t)(rg0 + j) * N + cg] = acc[m][n][j] + bv;
            }
        }
    }
}

// ---------------- fused pointwise attention ----------------
// grid: 1024 blocks x 256 threads; QBLK=64 (4 waves x 16 rows), KVBLK=64.
// AV is computed UNSCALED (no 1/(q+1)); k_ln compensates exactly via eps scaling.
__global__ __launch_bounds__(256, 4) void k_attn(
    const unsigned short* __restrict__ Qb,
    const unsigned short* __restrict__ Kb,
    const unsigned short* __restrict__ Vt,   // [1024][4096] = V transposed
    const float* __restrict__ rab,
    float* __restrict__ AV)
{
    __shared__ __align__(16) unsigned short sK[2][64 * 64];
    __shared__ __align__(16) unsigned short sVt[2][64 * 64];
    __shared__ __align__(16) unsigned short sP[64 * 64];   // 40 KB total

    const int tid = threadIdx.x;
    const int lane = tid & 63;
    const int w = tid >> 6;        // 0..3
    const int lr = lane & 15;
    const int lk = lane >> 4;

    const int bid = blockIdx.x;
    const int idx = bid & 255;
    const int g = bid >> 8;
    const int h = idx & 15;
    const int r_ = idx >> 4;
    const int bb = g >> 1;
    const int qt = (g & 1) ? (31 - r_) : r_;
    const int q0 = qt * 64;

    // Q fragments in registers (wave-private rows q0 + w*16 + lr)
    short8 qreg[2];
    #pragma unroll
    for (int ks = 0; ks < 2; ++ks)
        qreg[ks] = *(const short8*)(Qb + (((size_t)(bb * TSEQ + q0 + w * 16 + lr)) << 10)
                                     + h * 64 + ks * 32 + lk * 8);

    int qrow[4];
    const float* rabrow[4];
    const float* rabh = rab + (size_t)h * TSEQ * TSEQ;
    #pragma unroll
    for (int j = 0; j < 4; ++j) {
        qrow[j] = q0 + w * 16 + lk * 4 + j;
        rabrow[j] = rabh + (size_t)qrow[j] * TSEQ + lr;
    }

    f32x4 acc[4] = {};

    #define STAGE(buf, kt_) do {                                                      \
        int k0s = (kt_) * 64;                                                         \
        for (int c = tid; c < 512; c += 256) {                                        \
            int rr = c >> 3, kc = c & 7;                                              \
            int kcs = kc ^ (rr & 7);                                                  \
            gl_lds16(Kb + (((size_t)(bb * TSEQ + k0s + rr)) << 10) + h * 64 + kcs * 8,\
                     sK[buf] + c * 8);                                                \
            gl_lds16(Vt + (((size_t)(h * 64 + rr)) << 12) + bb * TSEQ + k0s + kcs * 8,\
                     sVt[buf] + c * 8);                                               \
        }                                                                             \
    } while (0)

    STAGE(0, 0);
    // rab for kt=0 into registers
    float rvc[4][4];
    #pragma unroll
    for (int nt = 0; nt < 4; ++nt)
        #pragma unroll
        for (int j = 0; j < 4; ++j)
            rvc[nt][j] = rabrow[j][nt * 16];
    __syncthreads();

    int cur = 0;
    for (int kt = 0; kt <= qt; ++kt) {
        const int k0 = kt * 64;
        const bool have_next = (kt < qt);
        if (have_next) STAGE(cur ^ 1, kt + 1);

        // prefetch next iteration's rab into regs (full iteration of cover)
        float rvn[4][4];
        if (have_next) {
            #pragma unroll
            for (int nt = 0; nt < 4; ++nt)
                #pragma unroll
                for (int j = 0; j < 4; ++j)
                    rvn[nt][j] = rabrow[j][k0 + 64 + nt * 16];
        }

        // S = Q K^T + rab  (alpha pre-folded into Q; rab as MFMA C-init)
        f32x4 s[4];
        #pragma unroll
        for (int nt = 0; nt < 4; ++nt) {
            f32x4 c0v;
            c0v[0] = rvc[nt][0]; c0v[1] = rvc[nt][1];
            c0v[2] = rvc[nt][2]; c0v[3] = rvc[nt][3];
            s[nt] = c0v;
        }
        #pragma unroll
        for (int ks = 0; ks < 2; ++ks) {
            #pragma unroll
            for (int nt = 0; nt < 4; ++nt)
                s[nt] = __builtin_amdgcn_mfma_f32_16x16x32_bf16(
                    qreg[ks], rd_swz(sK[cur], nt * 16 + lr, ks * 4 + lk), s[nt], 0, 0, 0);
        }

        // P = silu(s), causal (no 1/(q+1) — LN is scale-invariant)
        const bool full = (kt < qt);
        char* pb = (char*)sP;
        #pragma unroll
        for (int j = 0; j < 4; ++j) {
            const int prow = w * 16 + lk * 4 + j;
            char* bj = pb + prow * 128;
            const int swz = ((lk * 4 + j) & 7) << 4;   // == (prow & 7) << 4
            #pragma unroll
            for (int nt = 0; nt < 4; ++nt) {
                int k = k0 + nt * 16 + lr;
                float pv = (full || k <= qrow[j]) ? silu_f(s[nt][j]) : 0.f;
                *(unsigned short*)(bj + (((nt << 5) | (lr << 1)) ^ swz)) = f2bf(pv);
            }
        }

        // AV += P @ V
        #pragma unroll
        for (int ks = 0; ks < 2; ++ks) {
            short8 ap = rd_swz(sP, w * 16 + lr, ks * 4 + lk);
            #pragma unroll
            for (int dt = 0; dt < 4; ++dt)
                acc[dt] = __builtin_amdgcn_mfma_f32_16x16x32_bf16(
                    ap, rd_swz(sVt[cur], dt * 16 + lr, ks * 4 + lk), acc[dt], 0, 0, 0);
        }

        if (have_next) {
            #pragma unroll
            for (int nt = 0; nt < 4; ++nt)
                #pragma unroll
                for (int j = 0; j < 4; ++j)
                    rvc[nt][j] = rvn[nt][j];
        }

        __syncthreads();
        cur ^= 1;
    }
    #undef STAGE

    #pragma unroll
    for (int dt = 0; dt < 4; ++dt)
        #pragma unroll
        for (int j = 0; j < 4; ++j)
            AV[(((size_t)(bb * TSEQ + qrow[j])) << 10) + h * 64 + dt * 16 + lr] = acc[dt][j];
}

// ---------------- LayerNorm(AV) * U -> z (bf16) ----------------
// AV rows are scaled by c=(q+1) vs reference; LN(c*x) with eps*c^2 == LN(x) exactly.
__global__ __launch_bounds__(256) void k_ln(const float* __restrict__ AV,
                                            const float* __restrict__ U,
                                            const float* __restrict__ lnw,
                                            const float* __restrict__ lnb,
                                            unsigned short* __restrict__ z) {
    __shared__ float red[8];
    const int row = blockIdx.x, tid = threadIdx.x;
    const float c = (float)((row & (TSEQ - 1)) + 1);
    const float eps = 1e-5f * c * c;
    float4 v = ((const float4*)(AV + ((size_t)row << 10)))[tid];
    float s = v.x + v.y + v.z + v.w;
    float s2 = v.x * v.x + v.y * v.y + v.z * v.z + v.w * v.w;
    #pragma unroll
    for (int o = 32; o > 0; o >>= 1) { s += __shfl_xor(s, o); s2 += __shfl_xor(s2, o); }
    const int w = tid >> 6;
    if ((tid & 63) == 0) { red[w] = s; red[4 + w] = s2; }
    __syncthreads();
    s = red[0] + red[1] + red[2] + red[3];
    s2 = red[4] + red[5] + red[6] + red[7];
    const float mu = s * (1.f / 1024.f);
    const float var = s2 * (1.f / 1024.f) - mu * mu;
    const float rstd = rsqrtf(var + eps);
    float4 uw = ((const float4*)(U + ((size_t)row << 10)))[tid];
    float4 lw = ((const float4*)lnw)[tid];
    float4 lb = ((const float4*)lnb)[tid];
    union { unsigned short o[4]; uint2 u; } ov;
    ov.o[0] = f2bf(((v.x - mu) * rstd * lw.x + lb.x) * uw.x);
    ov.o[1] = f2bf(((v.y - mu) * rstd * lw.y + lb.y) * uw.y);
    ov.o[2] = f2bf(((v.z - mu) * rstd * lw.z + lb.z) * uw.z);
    ov.o[3] = f2bf(((v.w - mu) * rstd * lw.w + lb.w) * uw.w);
    ((uint2*)z)[((size_t)row << 8) + tid] = ov.u;
}

extern "C" void kernel_launch(void* const* d_in, const int* in_sizes, int n_in,
                              void* d_out, int out_size, void* d_ws, size_t ws_size,
                              hipStream_t stream) {
    const float* x     = (const float*)d_in[0];
    const float* rab   = (const float*)d_in[2];
    const float* W_in  = (const float*)d_in[3];
    const float* b_in  = (const float*)d_in[4];
    const float* W_out = (const float*)d_in[5];
    const float* b_out = (const float*)d_in[6];
    const float* ln_w  = (const float*)d_in[7];
    const float* ln_b  = (const float*)d_in[8];
    float* y = (float*)d_out;

    char* ws = (char*)d_ws;
    size_t off = 0;
    auto alloc = [&](size_t bytes) -> void* {
        void* p = ws + off;
        off += (bytes + 255) & ~(size_t)255;
        return p;
    };
    unsigned short* WinT  = (unsigned short*)alloc((size_t)4096 * 1024 * 2);
    unsigned short* WoutT = (unsigned short*)alloc((size_t)1024 * 1024 * 2);
    unsigned short* xb    = (unsigned short*)alloc((size_t)MROWS * DIM * 2);
    float*          Ubuf  = (float*)alloc((size_t)MROWS * DIM * 4);
    unsigned short* Qb    = (unsigned short*)alloc((size_t)MROWS * DIM * 2);
    unsigned short* Kb    = (unsigned short*)alloc((size_t)MROWS * DIM * 2);
    unsigned short* Vtb   = (unsigned short*)alloc((size_t)DIM * MROWS * 2);
    float*          AV    = (float*)alloc((size_t)MROWS * DIM * 4);
    unsigned short* z     = (unsigned short*)alloc((size_t)MROWS * DIM * 2);

    // prep
    k_convert<<<dim3(4096), dim3(256), 0, stream>>>(x, xb, MROWS * DIM / 4);
    k_transpose<<<dim3(128, 32), dim3(32, 8), 0, stream>>>(W_in, WinT, 1024, 4096);
    k_transpose<<<dim3(32, 32), dim3(32, 8), 0, stream>>>(W_out, WoutT, 1024, 1024);
    // GEMM1: h = silu(x @ W_in + b_in) -> U, V^T (fused transpose), Q(*alpha), K
    k_gemm<1><<<dim3(32, 32), dim3(256), 0, stream>>>(xb, WinT, MROWS, 4096, 1024,
                                                      b_in, Ubuf, Vtb, Qb, Kb, nullptr);
    // attention (AV unscaled)
    k_attn<<<dim3(1024), dim3(256), 0, stream>>>(Qb, Kb, Vtb, rab, AV);
    // LN * U (eps compensated per-row)
    k_ln<<<dim3(MROWS), dim3(256), 0, stream>>>(AV, Ubuf, ln_w, ln_b, z);
    // GEMM2: y = z @ W_out + b_out
    k_gemm<2><<<dim3(32, 8), dim3(256), 0, stream>>>(z, WoutT, MROWS, 1024, 1024,
                                                     b_out, nullptr, nullptr, nullptr, nullptr, y);
}

// Round 7
// 173.219 us; speedup vs baseline: 1.2808x; 1.0759x over previous
//
#include <hip/hip_runtime.h>

// Problem constants
#define BATCH 2
#define TSEQ 2048
#define DIM 1024
#define NH 16
#define HDIM 64
#define MROWS (BATCH * TSEQ)   // 4096

typedef __attribute__((ext_vector_type(4))) float f32x4;
typedef __attribute__((ext_vector_type(8))) short short8;

__device__ __forceinline__ unsigned short f2bf(float f) {
    union { float f; unsigned int u; } x; x.f = f;
    unsigned int r = x.u + 0x7fffu + ((x.u >> 16) & 1u);
    return (unsigned short)(r >> 16);
}

__device__ __forceinline__ float silu_f(float v) {
    return v * __builtin_amdgcn_rcpf(1.f + __expf(-v));
}

__device__ __forceinline__ void gl_lds16(const void* g, void* l) {
    __builtin_amdgcn_global_load_lds(
        (const __attribute__((address_space(1))) void*)g,
        (__attribute__((address_space(3))) void*)l, 16, 0, 0);
}

// swizzled LDS 16B-chunk read: row stride 128B, chunk index XOR (row&7)
__device__ __forceinline__ short8 rd_swz(const unsigned short* base, int row, int chunk) {
    const char* b = (const char*)base;
    return *(const short8*)(b + row * 128 + (((chunk ^ (row & 7)) << 4)));
}

// ---------------- prep: fp32 -> bf16 convert ----------------
__global__ __launch_bounds__(256) void k_convert(const float* __restrict__ in,
                                                 unsigned short* __restrict__ out,
                                                 int n4) {
    int i = blockIdx.x * 256 + threadIdx.x;
    if (i < n4) {
        float4 v = ((const float4*)in)[i];
        union { unsigned short s[4]; uint2 u; } o;
        o.s[0] = f2bf(v.x); o.s[1] = f2bf(v.y); o.s[2] = f2bf(v.z); o.s[3] = f2bf(v.w);
        ((uint2*)out)[i] = o.u;
    }
}

// ---------------- prep: transpose fp32 [R][C] -> bf16 [C][R] ----------------
__global__ __launch_bounds__(256) void k_transpose(const float* __restrict__ in,
                                                   unsigned short* __restrict__ out,
                                                   int R, int C) {
    __shared__ float tile[32][33];
    int tx = threadIdx.x, ty = threadIdx.y; // (32,8)
    int c0 = blockIdx.x * 32, r0 = blockIdx.y * 32;
    #pragma unroll
    for (int i = 0; i < 32; i += 8)
        tile[ty + i][tx] = in[(size_t)(r0 + ty + i) * C + c0 + tx];
    __syncthreads();
    #pragma unroll
    for (int i = 0; i < 32; i += 8)
        out[(size_t)(c0 + ty + i) * R + r0 + tx] = f2bf(tile[tx][ty + i]);
}

// ---------------- GEMM1: 256x256 tile, BK=64, 8 waves, 4-phase schedule ----------------
// C = A[4096,1024] @ Bt[4096,1024]^T; h = silu(C + bias); block's 256 cols lie
// entirely in one section: bn 0-3 -> U(f32), 4-7 -> V^T(bf16), 8-11 -> Q(*0.125), 12-15 -> K.
__device__ __forceinline__ void stage256(const unsigned short* __restrict__ A,
                                         const unsigned short* __restrict__ Bt,
                                         int row0, int col0, int k0,
                                         unsigned short* sAbuf, unsigned short* sBbuf,
                                         int tid) {
    #pragma unroll
    for (int q = 0; q < 4; ++q) {
        int c = tid + 512 * q;                       // chunk index 0..2047
        int rr = c >> 3;
        int kcs = (c & 7) ^ (rr & 7);                // pre-swizzled source chunk
        gl_lds16(A + (size_t)(row0 + rr) * 1024 + k0 + kcs * 8, sAbuf + c * 8);
        gl_lds16(Bt + (size_t)(col0 + rr) * 1024 + k0 + kcs * 8, sBbuf + c * 8);
    }
}

__global__ __launch_bounds__(512, 2) void k_gemm1_256(
    const unsigned short* __restrict__ A, const unsigned short* __restrict__ Bt,
    const float* __restrict__ bias,
    float* __restrict__ outU, unsigned short* __restrict__ outVt,
    unsigned short* __restrict__ outQ, unsigned short* __restrict__ outK)
{
    __shared__ __align__(16) unsigned short sA[2][256 * 64];
    __shared__ __align__(16) unsigned short sB[2][256 * 64];   // 128 KiB total

    const int tid = threadIdx.x;           // 0..511
    const int lane = tid & 63, wid = tid >> 6;
    const int lr = lane & 15, lk = lane >> 4;
    const int wm = wid >> 2, wn = wid & 3; // 2M x 4N wave grid
    const int bm = blockIdx.x, bn = blockIdx.y;
    const int row0 = bm * 256, col0 = bn * 256;

    f32x4 acc[8][4] = {};

    stage256(A, Bt, row0, col0, 0, sA[0], sB[0], tid);
    asm volatile("s_waitcnt vmcnt(0)" ::: "memory");
    __builtin_amdgcn_s_barrier();
    __builtin_amdgcn_sched_barrier(0);

    int cur = 0;
    for (int kt = 0; kt < 16; ++kt) {
        // phase 0 extras: issue next tile's loads (8 gl_lds) + B-frags for whole K-tile
        if (kt < 15) stage256(A, Bt, row0, col0, (kt + 1) * 64, sA[cur ^ 1], sB[cur ^ 1], tid);
        short8 bf[2][4];   // [kk][n], kept live across phases
        #pragma unroll
        for (int kk = 0; kk < 2; ++kk)
            #pragma unroll
            for (int n = 0; n < 4; ++n)
                bf[kk][n] = rd_swz(sB[cur], wn * 64 + n * 16 + lr, kk * 4 + lk);

        #pragma unroll
        for (int ph = 0; ph < 4; ++ph) {
            short8 af[2][2];   // [mm][kk]
            #pragma unroll
            for (int mm = 0; mm < 2; ++mm)
                #pragma unroll
                for (int kk = 0; kk < 2; ++kk)
                    af[mm][kk] = rd_swz(sA[cur], wm * 128 + (ph * 2 + mm) * 16 + lr, kk * 4 + lk);
            __builtin_amdgcn_s_barrier();
            __builtin_amdgcn_s_setprio(1);
            #pragma unroll
            for (int mm = 0; mm < 2; ++mm)
                #pragma unroll
                for (int n = 0; n < 4; ++n)
                    #pragma unroll
                    for (int kk = 0; kk < 2; ++kk)
                        acc[ph * 2 + mm][n] = __builtin_amdgcn_mfma_f32_16x16x32_bf16(
                            af[mm][kk], bf[kk][n], acc[ph * 2 + mm][n], 0, 0, 0);
            __builtin_amdgcn_s_setprio(0);
            if (ph == 3) asm volatile("s_waitcnt vmcnt(0)" ::: "memory");
            __builtin_amdgcn_s_barrier();
        }
        __builtin_amdgcn_sched_barrier(0);
        cur ^= 1;
    }

    // epilogue: whole block lies in one section
    const int sec = bn >> 2;
    #pragma unroll
    for (int n = 0; n < 4; ++n) {
        const int cg = col0 + wn * 64 + n * 16 + lr;
        const int cc = cg & 1023;
        const float bv = bias[cg];
        #pragma unroll
        for (int m = 0; m < 8; ++m) {
            const int rg0 = row0 + wm * 128 + m * 16 + lk * 4;
            float sv[4];
            #pragma unroll
            for (int j = 0; j < 4; ++j)
                sv[j] = silu_f(acc[m][n][j] + bv);
            if (sec == 0) {
                #pragma unroll
                for (int j = 0; j < 4; ++j)
                    outU[((size_t)(rg0 + j) << 10) + cc] = sv[j];
            } else if (sec == 1) {
                union { unsigned short s[4]; uint2 u; } pk;
                #pragma unroll
                for (int j = 0; j < 4; ++j) pk.s[j] = f2bf(sv[j]);
                *(uint2*)(outVt + ((size_t)cc << 12) + rg0) = pk.u;
            } else if (sec == 2) {
                #pragma unroll
                for (int j = 0; j < 4; ++j)
                    outQ[((size_t)(rg0 + j) << 10) + cc] = f2bf(sv[j] * 0.125f);
            } else {
                #pragma unroll
                for (int j = 0; j < 4; ++j)
                    outK[((size_t)(rg0 + j) << 10) + cc] = f2bf(sv[j]);
            }
        }
    }
}

// ---------------- GEMM2: C = A[M,K] @ Bt[N,K]^T (128^2 tile), y = acc + bias ----------------
__global__ __launch_bounds__(256) void k_gemm2(
    const unsigned short* __restrict__ A, const unsigned short* __restrict__ Bt,
    int M, int N, int K, const float* __restrict__ bias, float* __restrict__ outY)
{
    __shared__ __align__(16) unsigned short sA[128 * 32];
    __shared__ __align__(16) unsigned short sB[128 * 32];
    const int tid = threadIdx.x;
    const int bm = blockIdx.x, bn = blockIdx.y;
    const int row0 = bm * 128, col0 = bn * 128;
    const int lane = tid & 63, w = tid >> 6;
    const int wrow = (w >> 1) * 64, wcol = (w & 1) * 64;
    const int lr = lane & 15, lk = lane >> 4;

    f32x4 acc[4][4] = {};

    for (int k0 = 0; k0 < K; k0 += 32) {
        for (int c = tid; c < 512; c += 256) {
            int r = c >> 2, kc = c & 3;
            gl_lds16(A + (size_t)(row0 + r) * K + k0 + kc * 8, sA + c * 8);
            gl_lds16(Bt + (size_t)(col0 + r) * K + k0 + kc * 8, sB + c * 8);
        }
        __syncthreads();
        short8 af[4], bf[4];
        #pragma unroll
        for (int m = 0; m < 4; ++m)
            af[m] = *(const short8*)(sA + (wrow + m * 16 + lr) * 32 + lk * 8);
        #pragma unroll
        for (int n = 0; n < 4; ++n)
            bf[n] = *(const short8*)(sB + (wcol + n * 16 + lr) * 32 + lk * 8);
        #pragma unroll
        for (int m = 0; m < 4; ++m)
            #pragma unroll
            for (int n = 0; n < 4; ++n)
                acc[m][n] = __builtin_amdgcn_mfma_f32_16x16x32_bf16(af[m], bf[n], acc[m][n], 0, 0, 0);
        __syncthreads();
    }

    #pragma unroll
    for (int m = 0; m < 4; ++m) {
        #pragma unroll
        for (int n = 0; n < 4; ++n) {
            int cg = col0 + wcol + n * 16 + lr;
            float bv = bias[cg];
            int rg0 = row0 + wrow + m * 16 + lk * 4;
            #pragma unroll
            for (int j = 0; j < 4; ++j)
                outY[(size_t)(rg0 + j) * N + cg] = acc[m][n][j] + bv;
        }
    }
}

// ---------------- fused pointwise attention ----------------
// grid: 1024 blocks x 256 threads; QBLK=64 (4 waves x 16 rows), KVBLK=64.
// AV is computed UNSCALED (no 1/(q+1)); k_ln compensates exactly via eps scaling.
__global__ __launch_bounds__(256, 4) void k_attn(
    const unsigned short* __restrict__ Qb,
    const unsigned short* __restrict__ Kb,
    const unsigned short* __restrict__ Vt,   // [1024][4096] = V transposed
    const float* __restrict__ rab,
    float* __restrict__ AV)
{
    __shared__ __align__(16) unsigned short sK[2][64 * 64];
    __shared__ __align__(16) unsigned short sVt[2][64 * 64];
    __shared__ __align__(16) unsigned short sP[64 * 64];   // 40 KB total

    const int tid = threadIdx.x;
    const int lane = tid & 63;
    const int w = tid >> 6;        // 0..3
    const int lr = lane & 15;
    const int lk = lane >> 4;

    const int bid = blockIdx.x;
    const int idx = bid & 255;
    const int g = bid >> 8;
    const int h = idx & 15;
    const int r_ = idx >> 4;
    const int bb = g >> 1;
    const int qt = (g & 1) ? (31 - r_) : r_;
    const int q0 = qt * 64;

    // Q fragments in registers (wave-private rows q0 + w*16 + lr)
    short8 qreg[2];
    #pragma unroll
    for (int ks = 0; ks < 2; ++ks)
        qreg[ks] = *(const short8*)(Qb + (((size_t)(bb * TSEQ + q0 + w * 16 + lr)) << 10)
                                     + h * 64 + ks * 32 + lk * 8);

    int qrow[4];
    const float* rabrow[4];
    const float* rabh = rab + (size_t)h * TSEQ * TSEQ;
    #pragma unroll
    for (int j = 0; j < 4; ++j) {
        qrow[j] = q0 + w * 16 + lk * 4 + j;
        rabrow[j] = rabh + (size_t)qrow[j] * TSEQ + lr;
    }

    f32x4 acc[4] = {};

    #define STAGE(buf, kt_) do {                                                      \
        int k0s = (kt_) * 64;                                                         \
        for (int c = tid; c < 512; c += 256) {                                        \
            int rr = c >> 3, kc = c & 7;                                              \
            int kcs = kc ^ (rr & 7);                                                  \
            gl_lds16(Kb + (((size_t)(bb * TSEQ + k0s + rr)) << 10) + h * 64 + kcs * 8,\
                     sK[buf] + c * 8);                                                \
            gl_lds16(Vt + (((size_t)(h * 64 + rr)) << 12) + bb * TSEQ + k0s + kcs * 8,\
                     sVt[buf] + c * 8);                                               \
        }                                                                             \
    } while (0)

    STAGE(0, 0);
    // rab for kt=0 into registers
    float rvc[4][4];
    #pragma unroll
    for (int nt = 0; nt < 4; ++nt)
        #pragma unroll
        for (int j = 0; j < 4; ++j)
            rvc[nt][j] = rabrow[j][nt * 16];
    __syncthreads();

    int cur = 0;
    for (int kt = 0; kt <= qt; ++kt) {
        const int k0 = kt * 64;
        const bool have_next = (kt < qt);
        if (have_next) STAGE(cur ^ 1, kt + 1);

        // prefetch next iteration's rab into regs (full iteration of cover)
        float rvn[4][4];
        if (have_next) {
            #pragma unroll
            for (int nt = 0; nt < 4; ++nt)
                #pragma unroll
                for (int j = 0; j < 4; ++j)
                    rvn[nt][j] = rabrow[j][k0 + 64 + nt * 16];
        }

        // S = Q K^T + rab  (alpha pre-folded into Q; rab as MFMA C-init)
        f32x4 s[4];
        #pragma unroll
        for (int nt = 0; nt < 4; ++nt) {
            f32x4 c0v;
            c0v[0] = rvc[nt][0]; c0v[1] = rvc[nt][1];
            c0v[2] = rvc[nt][2]; c0v[3] = rvc[nt][3];
            s[nt] = c0v;
        }
        #pragma unroll
        for (int ks = 0; ks < 2; ++ks) {
            #pragma unroll
            for (int nt = 0; nt < 4; ++nt)
                s[nt] = __builtin_amdgcn_mfma_f32_16x16x32_bf16(
                    qreg[ks], rd_swz(sK[cur], nt * 16 + lr, ks * 4 + lk), s[nt], 0, 0, 0);
        }

        // P = silu(s), causal (no 1/(q+1) — LN is scale-invariant)
        const bool full = (kt < qt);
        char* pb = (char*)sP;
        #pragma unroll
        for (int j = 0; j < 4; ++j) {
            const int prow = w * 16 + lk * 4 + j;
            char* bj = pb + prow * 128;
            const int swz = ((lk * 4 + j) & 7) << 4;   // == (prow & 7) << 4
            #pragma unroll
            for (int nt = 0; nt < 4; ++nt) {
                int k = k0 + nt * 16 + lr;
                float pv = (full || k <= qrow[j]) ? silu_f(s[nt][j]) : 0.f;
                *(unsigned short*)(bj + (((nt << 5) | (lr << 1)) ^ swz)) = f2bf(pv);
            }
        }

        // AV += P @ V
        #pragma unroll
        for (int ks = 0; ks < 2; ++ks) {
            short8 ap = rd_swz(sP, w * 16 + lr, ks * 4 + lk);
            #pragma unroll
            for (int dt = 0; dt < 4; ++dt)
                acc[dt] = __builtin_amdgcn_mfma_f32_16x16x32_bf16(
                    ap, rd_swz(sVt[cur], dt * 16 + lr, ks * 4 + lk), acc[dt], 0, 0, 0);
        }

        if (have_next) {
            #pragma unroll
            for (int nt = 0; nt < 4; ++nt)
                #pragma unroll
                for (int j = 0; j < 4; ++j)
                    rvc[nt][j] = rvn[nt][j];
        }

        __syncthreads();
        cur ^= 1;
    }
    #undef STAGE

    #pragma unroll
    for (int dt = 0; dt < 4; ++dt)
        #pragma unroll
        for (int j = 0; j < 4; ++j)
            AV[(((size_t)(bb * TSEQ + qrow[j])) << 10) + h * 64 + dt * 16 + lr] = acc[dt][j];
}

// ---------------- LayerNorm(AV) * U -> z (bf16) ----------------
// AV rows are scaled by c=(q+1) vs reference; LN(c*x) with eps*c^2 == LN(x) exactly.
__global__ __launch_bounds__(256) void k_ln(const float* __restrict__ AV,
                                            const float* __restrict__ U,
                                            const float* __restrict__ lnw,
                                            const float* __restrict__ lnb,
                                            unsigned short* __restrict__ z) {
    __shared__ float red[8];
    const int row = blockIdx.x, tid = threadIdx.x;
    const float c = (float)((row & (TSEQ - 1)) + 1);
    const float eps = 1e-5f * c * c;
    float4 v = ((const float4*)(AV + ((size_t)row << 10)))[tid];
    float s = v.x + v.y + v.z + v.w;
    float s2 = v.x * v.x + v.y * v.y + v.z * v.z + v.w * v.w;
    #pragma unroll
    for (int o = 32; o > 0; o >>= 1) { s += __shfl_xor(s, o); s2 += __shfl_xor(s2, o); }
    const int w = tid >> 6;
    if ((tid & 63) == 0) { red[w] = s; red[4 + w] = s2; }
    __syncthreads();
    s = red[0] + red[1] + red[2] + red[3];
    s2 = red[4] + red[5] + red[6] + red[7];
    const float mu = s * (1.f / 1024.f);
    const float var = s2 * (1.f / 1024.f) - mu * mu;
    const float rstd = rsqrtf(var + eps);
    float4 uw = ((const float4*)(U + ((size_t)row << 10)))[tid];
    float4 lw = ((const float4*)lnw)[tid];
    float4 lb = ((const float4*)lnb)[tid];
    union { unsigned short o[4]; uint2 u; } ov;
    ov.o[0] = f2bf(((v.x - mu) * rstd * lw.x + lb.x) * uw.x);
    ov.o[1] = f2bf(((v.y - mu) * rstd * lw.y + lb.y) * uw.y);
    ov.o[2] = f2bf(((v.z - mu) * rstd * lw.z + lb.z) * uw.z);
    ov.o[3] = f2bf(((v.w - mu) * rstd * lw.w + lb.w) * uw.w);
    ((uint2*)z)[((size_t)row << 8) + tid] = ov.u;
}

extern "C" void kernel_launch(void* const* d_in, const int* in_sizes, int n_in,
                              void* d_out, int out_size, void* d_ws, size_t ws_size,
                              hipStream_t stream) {
    const float* x     = (const float*)d_in[0];
    const float* rab   = (const float*)d_in[2];
    const float* W_in  = (const float*)d_in[3];
    const float* b_in  = (const float*)d_in[4];
    const float* W_out = (const float*)d_in[5];
    const float* b_out = (const float*)d_in[6];
    const float* ln_w  = (const float*)d_in[7];
    const float* ln_b  = (const float*)d_in[8];
    float* y = (float*)d_out;

    char* ws = (char*)d_ws;
    size_t off = 0;
    auto alloc = [&](size_t bytes) -> void* {
        void* p = ws + off;
        off += (bytes + 255) & ~(size_t)255;
        return p;
    };
    unsigned short* WinT  = (unsigned short*)alloc((size_t)4096 * 1024 * 2);
    unsigned short* WoutT = (unsigned short*)alloc((size_t)1024 * 1024 * 2);
    unsigned short* xb    = (unsigned short*)alloc((size_t)MROWS * DIM * 2);
    float*          Ubuf  = (float*)alloc((size_t)MROWS * DIM * 4);
    unsigned short* Qb    = (unsigned short*)alloc((size_t)MROWS * DIM * 2);
    unsigned short* Kb    = (unsigned short*)alloc((size_t)MROWS * DIM * 2);
    unsigned short* Vtb   = (unsigned short*)alloc((size_t)DIM * MROWS * 2);
    float*          AV    = (float*)alloc((size_t)MROWS * DIM * 4);
    unsigned short* z     = (unsigned short*)alloc((size_t)MROWS * DIM * 2);

    // prep
    k_convert<<<dim3(4096), dim3(256), 0, stream>>>(x, xb, MROWS * DIM / 4);
    k_transpose<<<dim3(128, 32), dim3(32, 8), 0, stream>>>(W_in, WinT, 1024, 4096);
    k_transpose<<<dim3(32, 32), dim3(32, 8), 0, stream>>>(W_out, WoutT, 1024, 1024);
    // GEMM1 (256^2 4-phase): h = silu(x @ W_in + b_in) -> U, V^T, Q(*alpha), K
    k_gemm1_256<<<dim3(16, 16), dim3(512), 0, stream>>>(xb, WinT, b_in, Ubuf, Vtb, Qb, Kb);
    // attention (AV unscaled)
    k_attn<<<dim3(1024), dim3(256), 0, stream>>>(Qb, Kb, Vtb, rab, AV);
    // LN * U (eps compensated per-row)
    k_ln<<<dim3(MROWS), dim3(256), 0, stream>>>(AV, Ubuf, ln_w, ln_b, z);
    // GEMM2: y = z @ W_out + b_out
    k_gemm2<<<dim3(32, 8), dim3(256), 0, stream>>>(z, WoutT, MROWS, 1024, 1024, b_out, y);
}

// Round 8
// 170.729 us; speedup vs baseline: 1.2995x; 1.0146x over previous
//
#include <hip/hip_runtime.h>

// Problem constants
#define BATCH 2
#define TSEQ 2048
#define DIM 1024
#define NH 16
#define HDIM 64
#define MROWS (BATCH * TSEQ)   // 4096

typedef __attribute__((ext_vector_type(4))) float f32x4;
typedef __attribute__((ext_vector_type(8))) short short8;

__device__ __forceinline__ unsigned short f2bf(float f) {
    union { float f; unsigned int u; } x; x.f = f;
    unsigned int r = x.u + 0x7fffu + ((x.u >> 16) & 1u);
    return (unsigned short)(r >> 16);
}

__device__ __forceinline__ float silu_f(float v) {
    return v * __builtin_amdgcn_rcpf(1.f + __expf(-v));
}

__device__ __forceinline__ void gl_lds16(const void* g, void* l) {
    __builtin_amdgcn_global_load_lds(
        (const __attribute__((address_space(1))) void*)g,
        (__attribute__((address_space(3))) void*)l, 16, 0, 0);
}

// swizzled LDS 16B-chunk read: row stride 128B, chunk index XOR (row&7)
__device__ __forceinline__ short8 rd_swz(const unsigned short* base, int row, int chunk) {
    const char* b = (const char*)base;
    return *(const short8*)(b + row * 128 + (((chunk ^ (row & 7)) << 4)));
}

// ---------------- prep: fp32 -> bf16 convert ----------------
__global__ __launch_bounds__(256) void k_convert(const float* __restrict__ in,
                                                 unsigned short* __restrict__ out,
                                                 int n4) {
    int i = blockIdx.x * 256 + threadIdx.x;
    if (i < n4) {
        float4 v = ((const float4*)in)[i];
        union { unsigned short s[4]; uint2 u; } o;
        o.s[0] = f2bf(v.x); o.s[1] = f2bf(v.y); o.s[2] = f2bf(v.z); o.s[3] = f2bf(v.w);
        ((uint2*)out)[i] = o.u;
    }
}

// ---------------- prep: transpose fp32 [R][C] -> bf16 [C][R] ----------------
__global__ __launch_bounds__(256) void k_transpose(const float* __restrict__ in,
                                                   unsigned short* __restrict__ out,
                                                   int R, int C) {
    __shared__ float tile[32][33];
    int tx = threadIdx.x, ty = threadIdx.y; // (32,8)
    int c0 = blockIdx.x * 32, r0 = blockIdx.y * 32;
    #pragma unroll
    for (int i = 0; i < 32; i += 8)
        tile[ty + i][tx] = in[(size_t)(r0 + ty + i) * C + c0 + tx];
    __syncthreads();
    #pragma unroll
    for (int i = 0; i < 32; i += 8)
        out[(size_t)(c0 + ty + i) * R + r0 + tx] = f2bf(tile[tx][ty + i]);
}

// ---------------- GEMM1: 256x256 tile, BK=64, 8 waves, 4-phase schedule ----------------
__device__ __forceinline__ void stage256(const unsigned short* __restrict__ A,
                                         const unsigned short* __restrict__ Bt,
                                         int row0, int col0, int k0,
                                         unsigned short* sAbuf, unsigned short* sBbuf,
                                         int tid) {
    #pragma unroll
    for (int q = 0; q < 4; ++q) {
        int c = tid + 512 * q;                       // chunk index 0..2047
        int rr = c >> 3;
        int kcs = (c & 7) ^ (rr & 7);                // pre-swizzled source chunk
        gl_lds16(A + (size_t)(row0 + rr) * 1024 + k0 + kcs * 8, sAbuf + c * 8);
        gl_lds16(Bt + (size_t)(col0 + rr) * 1024 + k0 + kcs * 8, sBbuf + c * 8);
    }
}

__global__ __launch_bounds__(512, 2) void k_gemm1_256(
    const unsigned short* __restrict__ A, const unsigned short* __restrict__ Bt,
    const float* __restrict__ bias,
    float* __restrict__ outU, unsigned short* __restrict__ outVt,
    unsigned short* __restrict__ outQ, unsigned short* __restrict__ outK)
{
    __shared__ __align__(16) unsigned short sA[2][256 * 64];
    __shared__ __align__(16) unsigned short sB[2][256 * 64];   // 128 KiB total

    const int tid = threadIdx.x;           // 0..511
    const int lane = tid & 63, wid = tid >> 6;
    const int lr = lane & 15, lk = lane >> 4;
    const int wm = wid >> 2, wn = wid & 3; // 2M x 4N wave grid
    const int bm = blockIdx.x, bn = blockIdx.y;
    const int row0 = bm * 256, col0 = bn * 256;

    f32x4 acc[8][4] = {};

    stage256(A, Bt, row0, col0, 0, sA[0], sB[0], tid);
    asm volatile("s_waitcnt vmcnt(0)" ::: "memory");
    __builtin_amdgcn_s_barrier();
    __builtin_amdgcn_sched_barrier(0);

    int cur = 0;
    for (int kt = 0; kt < 16; ++kt) {
        // phase 0 extras: issue next tile's loads (8 gl_lds) + B-frags for whole K-tile
        if (kt < 15) stage256(A, Bt, row0, col0, (kt + 1) * 64, sA[cur ^ 1], sB[cur ^ 1], tid);
        short8 bf[2][4];   // [kk][n], kept live across phases
        #pragma unroll
        for (int kk = 0; kk < 2; ++kk)
            #pragma unroll
            for (int n = 0; n < 4; ++n)
                bf[kk][n] = rd_swz(sB[cur], wn * 64 + n * 16 + lr, kk * 4 + lk);

        #pragma unroll
        for (int ph = 0; ph < 4; ++ph) {
            short8 af[2][2];   // [mm][kk]
            #pragma unroll
            for (int mm = 0; mm < 2; ++mm)
                #pragma unroll
                for (int kk = 0; kk < 2; ++kk)
                    af[mm][kk] = rd_swz(sA[cur], wm * 128 + (ph * 2 + mm) * 16 + lr, kk * 4 + lk);
            __builtin_amdgcn_s_barrier();
            __builtin_amdgcn_s_setprio(1);
            #pragma unroll
            for (int mm = 0; mm < 2; ++mm)
                #pragma unroll
                for (int n = 0; n < 4; ++n)
                    #pragma unroll
                    for (int kk = 0; kk < 2; ++kk)
                        acc[ph * 2 + mm][n] = __builtin_amdgcn_mfma_f32_16x16x32_bf16(
                            af[mm][kk], bf[kk][n], acc[ph * 2 + mm][n], 0, 0, 0);
            __builtin_amdgcn_s_setprio(0);
            if (ph == 3) asm volatile("s_waitcnt vmcnt(0)" ::: "memory");
            __builtin_amdgcn_s_barrier();
        }
        __builtin_amdgcn_sched_barrier(0);
        cur ^= 1;
    }

    // epilogue: whole block lies in one section
    const int sec = bn >> 2;
    #pragma unroll
    for (int n = 0; n < 4; ++n) {
        const int cg = col0 + wn * 64 + n * 16 + lr;
        const int cc = cg & 1023;
        const float bv = bias[cg];
        #pragma unroll
        for (int m = 0; m < 8; ++m) {
            const int rg0 = row0 + wm * 128 + m * 16 + lk * 4;
            float sv[4];
            #pragma unroll
            for (int j = 0; j < 4; ++j)
                sv[j] = silu_f(acc[m][n][j] + bv);
            if (sec == 0) {
                #pragma unroll
                for (int j = 0; j < 4; ++j)
                    outU[((size_t)(rg0 + j) << 10) + cc] = sv[j];
            } else if (sec == 1) {
                union { unsigned short s[4]; uint2 u; } pk;
                #pragma unroll
                for (int j = 0; j < 4; ++j) pk.s[j] = f2bf(sv[j]);
                *(uint2*)(outVt + ((size_t)cc << 12) + rg0) = pk.u;
            } else if (sec == 2) {
                #pragma unroll
                for (int j = 0; j < 4; ++j)
                    outQ[((size_t)(rg0 + j) << 10) + cc] = f2bf(sv[j] * 0.125f);
            } else {
                #pragma unroll
                for (int j = 0; j < 4; ++j)
                    outK[((size_t)(rg0 + j) << 10) + cc] = f2bf(sv[j]);
            }
        }
    }
}

// ---------------- GEMM2: C = A[M,K] @ Bt[N,K]^T (128^2 tile), y = acc + bias ----------------
__global__ __launch_bounds__(256) void k_gemm2(
    const unsigned short* __restrict__ A, const unsigned short* __restrict__ Bt,
    int M, int N, int K, const float* __restrict__ bias, float* __restrict__ outY)
{
    __shared__ __align__(16) unsigned short sA[128 * 32];
    __shared__ __align__(16) unsigned short sB[128 * 32];
    const int tid = threadIdx.x;
    const int bm = blockIdx.x, bn = blockIdx.y;
    const int row0 = bm * 128, col0 = bn * 128;
    const int lane = tid & 63, w = tid >> 6;
    const int wrow = (w >> 1) * 64, wcol = (w & 1) * 64;
    const int lr = lane & 15, lk = lane >> 4;

    f32x4 acc[4][4] = {};

    for (int k0 = 0; k0 < K; k0 += 32) {
        for (int c = tid; c < 512; c += 256) {
            int r = c >> 2, kc = c & 3;
            gl_lds16(A + (size_t)(row0 + r) * K + k0 + kc * 8, sA + c * 8);
            gl_lds16(Bt + (size_t)(col0 + r) * K + k0 + kc * 8, sB + c * 8);
        }
        __syncthreads();
        short8 af[4], bf[4];
        #pragma unroll
        for (int m = 0; m < 4; ++m)
            af[m] = *(const short8*)(sA + (wrow + m * 16 + lr) * 32 + lk * 8);
        #pragma unroll
        for (int n = 0; n < 4; ++n)
            bf[n] = *(const short8*)(sB + (wcol + n * 16 + lr) * 32 + lk * 8);
        #pragma unroll
        for (int m = 0; m < 4; ++m)
            #pragma unroll
            for (int n = 0; n < 4; ++n)
                acc[m][n] = __builtin_amdgcn_mfma_f32_16x16x32_bf16(af[m], bf[n], acc[m][n], 0, 0, 0);
        __syncthreads();
    }

    #pragma unroll
    for (int m = 0; m < 4; ++m) {
        #pragma unroll
        for (int n = 0; n < 4; ++n) {
            int cg = col0 + wcol + n * 16 + lr;
            float bv = bias[cg];
            int rg0 = row0 + wrow + m * 16 + lk * 4;
            #pragma unroll
            for (int j = 0; j < 4; ++j)
                outY[(size_t)(rg0 + j) * N + cg] = acc[m][n][j] + bv;
        }
    }
}

// ---------------- fused pointwise attention ----------------
// grid: 1024 blocks x 256 threads; QBLK=64 (4 waves x 16 rows), KVBLK=64.
// AV is UNSCALED (no 1/(q+1)); k_ln compensates exactly via eps scaling.
// Loop uses raw s_barrier + counted vmcnt(16): drains exactly the 4 staging
// gl_lds (oldest), keeps the 16 rab dword loads in flight across the barrier.
__global__ __launch_bounds__(256, 4) void k_attn(
    const unsigned short* __restrict__ Qb,
    const unsigned short* __restrict__ Kb,
    const unsigned short* __restrict__ Vt,   // [1024][4096] = V transposed
    const float* __restrict__ rab,
    float* __restrict__ AV)
{
    __shared__ __align__(16) unsigned short sK[2][64 * 64];
    __shared__ __align__(16) unsigned short sVt[2][64 * 64];
    __shared__ __align__(16) unsigned short sP[64 * 64];   // 40 KB total

    const int tid = threadIdx.x;
    const int lane = tid & 63;
    const int w = tid >> 6;        // 0..3
    const int lr = lane & 15;
    const int lk = lane >> 4;

    const int bid = blockIdx.x;
    const int idx = bid & 255;
    const int g = bid >> 8;
    const int h = idx & 15;
    const int r_ = idx >> 4;
    const int bb = g >> 1;
    const int qt = (g & 1) ? (31 - r_) : r_;
    const int q0 = qt * 64;

    // Q fragments in registers (wave-private rows q0 + w*16 + lr)
    short8 qreg[2];
    #pragma unroll
    for (int ks = 0; ks < 2; ++ks)
        qreg[ks] = *(const short8*)(Qb + (((size_t)(bb * TSEQ + q0 + w * 16 + lr)) << 10)
                                     + h * 64 + ks * 32 + lk * 8);
    __builtin_amdgcn_sched_barrier(0);

    int qrow[4];
    const float* rabrow[4];
    const float* rabh = rab + (size_t)h * TSEQ * TSEQ;
    #pragma unroll
    for (int j = 0; j < 4; ++j) {
        qrow[j] = q0 + w * 16 + lk * 4 + j;
        rabrow[j] = rabh + (size_t)qrow[j] * TSEQ + lr;
    }

    f32x4 acc[4] = {};

    #define STAGE(buf, kt_) do {                                                      \
        int k0s = (kt_) * 64;                                                         \
        for (int c = tid; c < 512; c += 256) {                                        \
            int rr = c >> 3, kc = c & 7;                                              \
            int kcs = kc ^ (rr & 7);                                                  \
            gl_lds16(Kb + (((size_t)(bb * TSEQ + k0s + rr)) << 10) + h * 64 + kcs * 8,\
                     sK[buf] + c * 8);                                                \
            gl_lds16(Vt + (((size_t)(h * 64 + rr)) << 12) + bb * TSEQ + k0s + kcs * 8,\
                     sVt[buf] + c * 8);                                               \
        }                                                                             \
    } while (0)

    float rv0[4][4], rv1[4][4];

    STAGE(0, 0);
    __builtin_amdgcn_sched_barrier(0);
    // rab for kt=0 into rv0 (issued after staging -> staging is oldest)
    #pragma unroll
    for (int nt = 0; nt < 4; ++nt)
        #pragma unroll
        for (int j = 0; j < 4; ++j)
            rv0[nt][j] = rabrow[j][nt * 16];
    __builtin_amdgcn_sched_barrier(0);
    // drain Q-loads (2) + stage (4); keep the 16 rab loads in flight
    asm volatile("s_waitcnt vmcnt(16)" ::: "memory");
    __builtin_amdgcn_s_barrier();

    // One iteration body. RVC = this iter's rab (in regs); RVN = next iter's (loaded here).
    #define BODY(KT, BUFC, RVC, RVN) do {                                             \
        const int k0 = (KT) * 64;                                                     \
        const bool have_next = (KT) < qt;                                             \
        if (have_next) STAGE((BUFC) ^ 1, (KT) + 1);                                   \
        __builtin_amdgcn_sched_barrier(0);                                            \
        if (have_next) {                                                              \
            _Pragma("unroll")                                                         \
            for (int nt = 0; nt < 4; ++nt)                                            \
                _Pragma("unroll")                                                     \
                for (int j = 0; j < 4; ++j)                                           \
                    RVN[nt][j] = rabrow[j][k0 + 64 + nt * 16];                        \
        }                                                                             \
        __builtin_amdgcn_sched_barrier(0);                                            \
        f32x4 s[4];                                                                   \
        _Pragma("unroll")                                                             \
        for (int nt = 0; nt < 4; ++nt) {                                              \
            f32x4 c0v;                                                                \
            c0v[0] = RVC[nt][0]; c0v[1] = RVC[nt][1];                                 \
            c0v[2] = RVC[nt][2]; c0v[3] = RVC[nt][3];                                 \
            s[nt] = c0v;                                                              \
        }                                                                             \
        _Pragma("unroll")                                                             \
        for (int ks = 0; ks < 2; ++ks) {                                              \
            _Pragma("unroll")                                                         \
            for (int nt = 0; nt < 4; ++nt)                                            \
                s[nt] = __builtin_amdgcn_mfma_f32_16x16x32_bf16(                      \
                    qreg[ks], rd_swz(sK[BUFC], nt * 16 + lr, ks * 4 + lk), s[nt], 0, 0, 0); \
        }                                                                             \
        char* pb = (char*)sP;                                                         \
        if (have_next) {                                                              \
            _Pragma("unroll")                                                         \
            for (int j = 0; j < 4; ++j) {                                             \
                const int prow = w * 16 + lk * 4 + j;                                 \
                char* bj = pb + prow * 128;                                           \
                const int swz = ((lk * 4 + j) & 7) << 4;                              \
                _Pragma("unroll")                                                     \
                for (int nt = 0; nt < 4; ++nt)                                        \
                    *(unsigned short*)(bj + (((nt << 5) | (lr << 1)) ^ swz))          \
                        = f2bf(silu_f(s[nt][j]));                                     \
            }                                                                         \
        } else {                                                                      \
            _Pragma("unroll")                                                         \
            for (int j = 0; j < 4; ++j) {                                             \
                const int prow = w * 16 + lk * 4 + j;                                 \
                char* bj = pb + prow * 128;                                           \
                const int swz = ((lk * 4 + j) & 7) << 4;                              \
                _Pragma("unroll")                                                     \
                for (int nt = 0; nt < 4; ++nt) {                                      \
                    int k = k0 + nt * 16 + lr;                                        \
                    float pv = (k <= qrow[j]) ? silu_f(s[nt][j]) : 0.f;               \
                    *(unsigned short*)(bj + (((nt << 5) | (lr << 1)) ^ swz)) = f2bf(pv); \
                }                                                                     \
            }                                                                         \
        }                                                                             \
        _Pragma("unroll")                                                             \
        for (int ks = 0; ks < 2; ++ks) {                                              \
            short8 ap = rd_swz(sP, w * 16 + lr, ks * 4 + lk);                         \
            _Pragma("unroll")                                                         \
            for (int dt = 0; dt < 4; ++dt)                                            \
                acc[dt] = __builtin_amdgcn_mfma_f32_16x16x32_bf16(                    \
                    ap, rd_swz(sVt[BUFC], dt * 16 + lr, ks * 4 + lk), acc[dt], 0, 0, 0); \
        }                                                                             \
        if (have_next) {                                                              \
            asm volatile("s_waitcnt vmcnt(16)" ::: "memory");                         \
            __builtin_amdgcn_s_barrier();                                             \
        }                                                                             \
    } while (0)

    for (int kt = 0; kt <= qt; kt += 2) {
        BODY(kt, 0, rv0, rv1);
        if (kt + 1 <= qt) BODY(kt + 1, 1, rv1, rv0);
    }
    #undef BODY
    #undef STAGE

    #pragma unroll
    for (int dt = 0; dt < 4; ++dt)
        #pragma unroll
        for (int j = 0; j < 4; ++j)
            AV[(((size_t)(bb * TSEQ + qrow[j])) << 10) + h * 64 + dt * 16 + lr] = acc[dt][j];
}

// ---------------- LayerNorm(AV) * U -> z (bf16) ----------------
// AV rows are scaled by c=(q+1) vs reference; LN(c*x) with eps*c^2 == LN(x) exactly.
__global__ __launch_bounds__(256) void k_ln(const float* __restrict__ AV,
                                            const float* __restrict__ U,
                                            const float* __restrict__ lnw,
                                            const float* __restrict__ lnb,
                                            unsigned short* __restrict__ z) {
    __shared__ float red[8];
    const int row = blockIdx.x, tid = threadIdx.x;
    const float c = (float)((row & (TSEQ - 1)) + 1);
    const float eps = 1e-5f * c * c;
    float4 v = ((const float4*)(AV + ((size_t)row << 10)))[tid];
    float s = v.x + v.y + v.z + v.w;
    float s2 = v.x * v.x + v.y * v.y + v.z * v.z + v.w * v.w;
    #pragma unroll
    for (int o = 32; o > 0; o >>= 1) { s += __shfl_xor(s, o); s2 += __shfl_xor(s2, o); }
    const int w = tid >> 6;
    if ((tid & 63) == 0) { red[w] = s; red[4 + w] = s2; }
    __syncthreads();
    s = red[0] + red[1] + red[2] + red[3];
    s2 = red[4] + red[5] + red[6] + red[7];
    const float mu = s * (1.f / 1024.f);
    const float var = s2 * (1.f / 1024.f) - mu * mu;
    const float rstd = rsqrtf(var + eps);
    float4 uw = ((const float4*)(U + ((size_t)row << 10)))[tid];
    float4 lw = ((const float4*)lnw)[tid];
    float4 lb = ((const float4*)lnb)[tid];
    union { unsigned short o[4]; uint2 u; } ov;
    ov.o[0] = f2bf(((v.x - mu) * rstd * lw.x + lb.x) * uw.x);
    ov.o[1] = f2bf(((v.y - mu) * rstd * lw.y + lb.y) * uw.y);
    ov.o[2] = f2bf(((v.z - mu) * rstd * lw.z + lb.z) * uw.z);
    ov.o[3] = f2bf(((v.w - mu) * rstd * lw.w + lb.w) * uw.w);
    ((uint2*)z)[((size_t)row << 8) + tid] = ov.u;
}

extern "C" void kernel_launch(void* const* d_in, const int* in_sizes, int n_in,
                              void* d_out, int out_size, void* d_ws, size_t ws_size,
                              hipStream_t stream) {
    const float* x     = (const float*)d_in[0];
    const float* rab   = (const float*)d_in[2];
    const float* W_in  = (const float*)d_in[3];
    const float* b_in  = (const float*)d_in[4];
    const float* W_out = (const float*)d_in[5];
    const float* b_out = (const float*)d_in[6];
    const float* ln_w  = (const float*)d_in[7];
    const float* ln_b  = (const float*)d_in[8];
    float* y = (float*)d_out;

    char* ws = (char*)d_ws;
    size_t off = 0;
    auto alloc = [&](size_t bytes) -> void* {
        void* p = ws + off;
        off += (bytes + 255) & ~(size_t)255;
        return p;
    };
    unsigned short* WinT  = (unsigned short*)alloc((size_t)4096 * 1024 * 2);
    unsigned short* WoutT = (unsigned short*)alloc((size_t)1024 * 1024 * 2);
    unsigned short* xb    = (unsigned short*)alloc((size_t)MROWS * DIM * 2);
    float*          Ubuf  = (float*)alloc((size_t)MROWS * DIM * 4);
    unsigned short* Qb    = (unsigned short*)alloc((size_t)MROWS * DIM * 2);
    unsigned short* Kb    = (unsigned short*)alloc((size_t)MROWS * DIM * 2);
    unsigned short* Vtb   = (unsigned short*)alloc((size_t)DIM * MROWS * 2);
    float*          AV    = (float*)alloc((size_t)MROWS * DIM * 4);
    unsigned short* z     = (unsigned short*)alloc((size_t)MROWS * DIM * 2);

    // prep
    k_convert<<<dim3(4096), dim3(256), 0, stream>>>(x, xb, MROWS * DIM / 4);
    k_transpose<<<dim3(128, 32), dim3(32, 8), 0, stream>>>(W_in, WinT, 1024, 4096);
    k_transpose<<<dim3(32, 32), dim3(32, 8), 0, stream>>>(W_out, WoutT, 1024, 1024);
    // GEMM1 (256^2 4-phase): h = silu(x @ W_in + b_in) -> U, V^T, Q(*alpha), K
    k_gemm1_256<<<dim3(16, 16), dim3(512), 0, stream>>>(xb, WinT, b_in, Ubuf, Vtb, Qb, Kb);
    // attention (AV unscaled)
    k_attn<<<dim3(1024), dim3(256), 0, stream>>>(Qb, Kb, Vtb, rab, AV);
    // LN * U (eps compensated per-row)
    k_ln<<<dim3(MROWS), dim3(256), 0, stream>>>(AV, Ubuf, ln_w, ln_b, z);
    // GEMM2: y = z @ W_out + b_out
    k_gemm2<<<dim3(32, 8), dim3(256), 0, stream>>>(z, WoutT, MROWS, 1024, 1024, b_out, y);
}